// Round 10
// baseline (110.993 us; speedup 1.0000x reference)
//
#include <hip/hip_runtime.h>
#include <hip/hip_bf16.h>

typedef __attribute__((ext_vector_type(8))) _Float16 f16x8;
typedef __attribute__((ext_vector_type(4))) float f32x4;

#define NWIN 49
#define NH 8
#define CCH 256
#define PROW 72   // ushort stride for P rows (144B, 16B-aligned)

// cvt_pkrtz returns '__fp16 ext_vector(2)' — bit-cast through uint to avoid type friction
__device__ __forceinline__ uint cvt2_u32(float a, float b) {
    auto t = __builtin_amdgcn_cvt_pkrtz(a, b);
    return *(uint*)&t;
}
__device__ __forceinline__ f16x8 mk8(uint a, uint b, uint c, uint d) {
    union { uint u[4]; f16x8 v; } x;
    x.u[0] = a; x.u[1] = b; x.u[2] = c; x.u[3] = d;
    return x.v;
}
__device__ __forceinline__ ushort4 pack4(uint a, uint b) {
    union { uint u[2]; ushort4 s; } x;
    x.u[0] = a; x.u[1] = b;
    return x.s;
}

// --- Kernel A: pos MLP table, (169, 8) fp32 ---
__global__ void pos_mlp_kernel(const float* __restrict__ W1, const float* __restrict__ b1,
                               const float* __restrict__ W2, const float* __restrict__ b2,
                               float* __restrict__ pos) {
    int idx = blockIdx.x * blockDim.x + threadIdx.x;
    if (idx >= 169) return;
    float bh = (float)(idx / 13) - 6.0f;
    float bw = (float)(idx % 13) - 6.0f;
    float outv[NH];
#pragma unroll
    for (int t = 0; t < NH; ++t) outv[t] = b2[t];
    for (int u = 0; u < 64; ++u) {
        float hv = fmaf(bh, W1[u], fmaf(bw, W1[64 + u], b1[u]));
        hv = fmaxf(hv, 0.0f);
#pragma unroll
        for (int t = 0; t < NH; ++t) outv[t] = fmaf(hv, W2[u * NH + t], outv[t]);
    }
#pragma unroll
    for (int t = 0; t < NH; ++t) pos[idx * NH + t] = outv[t];
}

// --- Kernel B: bias (×log2e) in S^T MFMA C/D fragment layout, -1e30 mask for j>=49 ---
__global__ void bias_frag_kernel(const float* __restrict__ pos, float* __restrict__ bfrag) {
    int blk = blockIdx.x;           // ((h*4 + jt)*4 + it), 128 blocks
    int it = blk & 3, jt = (blk >> 2) & 3, h = blk >> 4;
    int lane = threadIdx.x;
    int g = lane >> 4, l15 = lane & 15;
    int i = it * 16 + l15;
    float4 v;
    float* vp = (float*)&v;
#pragma unroll
    for (int r = 0; r < 4; ++r) {
        int j = jt * 16 + g * 4 + r;
        float val;
        if (j >= NWIN) val = -1e30f;                       // exp2 -> 0 (kills clamped K rows)
        else if (i >= NWIN) val = 0.0f;
        else {
            int rel = (i / 7 - j / 7 + 6) * 13 + (i % 7 - j % 7 + 6);
            val = pos[rel * NH + h] * 1.4426950408889634f; // fold log2e
        }
        vp[r] = val;
    }
    *(float4*)(bfrag + (size_t)blk * 256 + lane * 4) = v;
}

// --- Kernel C: 512 threads = 8 waves = ALL 8 heads of ONE window (wave w = head w).
//     fp16 single-pass MFMA; ALL loads issued up front, pinned in consumption order.
__global__ __launch_bounds__(512, 2) void attn_kernel(
    const float* __restrict__ q, const float* __restrict__ k,
    const float* __restrict__ v, const float* __restrict__ bfrag,
    float* __restrict__ out) {
    __shared__ __align__(16) ushort sP[8][64 * PROW];   // 73728 B

    // Bijective XCD swizzle (gridDim.x = 2048, divisible by 8)
    const int nper = (int)(gridDim.x >> 3);
    const int b = ((int)blockIdx.x & 7) * nper + ((int)blockIdx.x >> 3);

    const int tid = threadIdx.x;
    const int w = tid >> 6, lane = tid & 63;   // w = head
    const int h = w;
    const int g = lane >> 4, l15 = lane & 15;
    const size_t base = (size_t)b * (NWIN * CCH) + h * 32;
    ushort* myP = sP[w];

    // ======== Phase 0: ISSUE all global loads (QK, V, bias) ========
    float4 kraw[4][2], qraw[4][2];
#pragma unroll
    for (int t = 0; t < 4; ++t) {
        int row = t * 16 + l15;
        int rc = row < NWIN ? row : NWIN - 1;    // clamp: garbage killed downstream
        const float* kp = k + base + (size_t)rc * CCH + g * 8;
        const float* qp = q + base + (size_t)rc * CCH + g * 8;
        kraw[t][0] = *(const float4*)kp; kraw[t][1] = *(const float4*)(kp + 4);
        qraw[t][0] = *(const float4*)qp; qraw[t][1] = *(const float4*)(qp + 4);
    }
    float vv[2][2][8];   // V B-frag elements (rows j=ks*32+g*8+e clamped, col d=nt*16+l15)
#pragma unroll
    for (int ks = 0; ks < 2; ++ks)
#pragma unroll
        for (int nt = 0; nt < 2; ++nt)
#pragma unroll
            for (int e = 0; e < 8; ++e) {
                int j = ks * 32 + g * 8 + e;
                int jc = j < NWIN ? j : NWIN - 1;   // P[j>=49]=0 -> contributes 0
                vv[ks][nt][e] = v[base + (size_t)jc * CCH + nt * 16 + l15];
            }
    f32x4 bb[4][4];      // [jt][it] bias fragments (L2-hot table)
#pragma unroll
    for (int jt = 0; jt < 4; ++jt)
#pragma unroll
        for (int it = 0; it < 4; ++it)
            bb[jt][it] = *(const f32x4*)(bfrag + (size_t)((h * 4 + jt) * 4 + it) * 256 + lane * 4);

    // ---- pin QK results (drains QK; V/bias stay in flight) ----
#pragma unroll
    for (int t = 0; t < 4; ++t)
        asm volatile("" :: "v"(kraw[t][0].x), "v"(kraw[t][1].x),
                           "v"(qraw[t][0].x), "v"(qraw[t][1].x));

    // ======== Phase 1: convert Q/K to fp16 fragments (single pass, RTZ) ========
    f16x8 ka16[4], qb16[4];
#pragma unroll
    for (int t = 0; t < 4; ++t) {
        float4 a = kraw[t][0], c = kraw[t][1];
        ka16[t] = mk8(cvt2_u32(a.x, a.y), cvt2_u32(a.z, a.w),
                      cvt2_u32(c.x, c.y), cvt2_u32(c.z, c.w));
        float4 d = qraw[t][0], e = qraw[t][1];
        qb16[t] = mk8(cvt2_u32(d.x, d.y), cvt2_u32(d.z, d.w),
                      cvt2_u32(e.x, e.y), cvt2_u32(e.z, e.w));
    }

    // ======== Phase 2: QK^T (swapped): acc[jt][it] = S^T tile, 1 MFMA each ========
    f32x4 acc[4][4];
#pragma unroll
    for (int jt = 0; jt < 4; ++jt)
#pragma unroll
        for (int it = 0; it < 4; ++it) {
            f32x4 a = {0.f, 0.f, 0.f, 0.f};
            acc[jt][it] = __builtin_amdgcn_mfma_f32_16x16x32_f16(ka16[jt], qb16[it], a, 0, 0, 0);
        }

    // ---- pin bias (was in flight under convert+MFMA) ----
#pragma unroll
    for (int jt = 0; jt < 4; ++jt)
        asm volatile("" :: "v"(bb[jt][0].x), "v"(bb[jt][1].x),
                           "v"(bb[jt][2].x), "v"(bb[jt][3].x));

    // ======== Phase 3: softmax per column i; P -> LDS fp16 ========
    const float scale2 = 0.17677669529663687f * 1.4426950408889634f;
#pragma unroll
    for (int it = 0; it < 4; ++it) {
        float p[16];
        float s = 0.0f;
#pragma unroll
        for (int jt = 0; jt < 4; ++jt)
#pragma unroll
            for (int r = 0; r < 4; ++r) {
                float e = __builtin_amdgcn_exp2f(fmaf(acc[jt][it][r], scale2, bb[jt][it][r]));
                p[jt * 4 + r] = e;
                s += e;
            }
        s += __shfl_xor(s, 16);
        s += __shfl_xor(s, 32);
        const float inv = 1.0f / s;
#pragma unroll
        for (int jt = 0; jt < 4; ++jt) {
            uint a01 = cvt2_u32(p[jt * 4 + 0] * inv, p[jt * 4 + 1] * inv);
            uint a23 = cvt2_u32(p[jt * 4 + 2] * inv, p[jt * 4 + 3] * inv);
            *(ushort4*)&myP[(it * 16 + l15) * PROW + jt * 16 + g * 4] = pack4(a01, a23);
        }
    }

    // ---- pin V (arrived long ago) + convert to fp16 B-frags ----
#pragma unroll
    for (int ks = 0; ks < 2; ++ks)
#pragma unroll
        for (int nt = 0; nt < 2; ++nt)
            asm volatile("" :: "v"(vv[ks][nt][0]), "v"(vv[ks][nt][1]),
                               "v"(vv[ks][nt][2]), "v"(vv[ks][nt][3]),
                               "v"(vv[ks][nt][4]), "v"(vv[ks][nt][5]),
                               "v"(vv[ks][nt][6]), "v"(vv[ks][nt][7]));
    f16x8 bv[2][2];
#pragma unroll
    for (int ks = 0; ks < 2; ++ks)
#pragma unroll
        for (int nt = 0; nt < 2; ++nt)
            bv[ks][nt] = mk8(cvt2_u32(vv[ks][nt][0], vv[ks][nt][1]),
                             cvt2_u32(vv[ks][nt][2], vv[ks][nt][3]),
                             cvt2_u32(vv[ks][nt][4], vv[ks][nt][5]),
                             cvt2_u32(vv[ks][nt][6], vv[ks][nt][7]));

    // ======== Phase 4: PV (P A-frags from private LDS; same-wave, no barrier) ========
    f32x4 oacc[4][2];
#pragma unroll
    for (int mt = 0; mt < 4; ++mt)
#pragma unroll
        for (int nt = 0; nt < 2; ++nt) oacc[mt][nt] = (f32x4){0.f, 0.f, 0.f, 0.f};
#pragma unroll
    for (int ks = 0; ks < 2; ++ks)
#pragma unroll
        for (int mt = 0; mt < 4; ++mt) {
            f16x8 pa = *(const f16x8*)&myP[(mt * 16 + l15) * PROW + ks * 32 + g * 8];
#pragma unroll
            for (int nt = 0; nt < 2; ++nt)
                oacc[mt][nt] = __builtin_amdgcn_mfma_f32_16x16x32_f16(pa, bv[ks][nt], oacc[mt][nt], 0, 0, 0);
        }

    // ======== Phase 5: store (4x64B segments per instruction; 8 waves cover full rows) ========
#pragma unroll
    for (int mt = 0; mt < 4; ++mt)
#pragma unroll
        for (int r = 0; r < 4; ++r) {
            int i = mt * 16 + g * 4 + r;
            if (i < NWIN) {
                float* op = out + base + (size_t)i * CCH + l15;
                op[0]  = oacc[mt][0][r];
                op[16] = oacc[mt][1][r];
            }
        }
}

extern "C" void kernel_launch(void* const* d_in, const int* in_sizes, int n_in,
                              void* d_out, int out_size, void* d_ws, size_t ws_size,
                              hipStream_t stream) {
    const float* q  = (const float*)d_in[0];
    const float* k  = (const float*)d_in[1];
    const float* v  = (const float*)d_in[2];
    const float* W1 = (const float*)d_in[3];
    const float* b1 = (const float*)d_in[4];
    const float* W2 = (const float*)d_in[5];
    const float* b2 = (const float*)d_in[6];

    float* pos   = (float*)d_ws;                       // 169*8 fp32
    float* bfrag = (float*)((char*)d_ws + 8192);       // 128*256 fp32 = 131072 B
    float* out   = (float*)d_out;

    const int B = in_sizes[0] / (NWIN * CCH);          // 2048 (divisible by 8)

    pos_mlp_kernel<<<1, 192, 0, stream>>>(W1, b1, W2, b2, pos);
    bias_frag_kernel<<<128, 64, 0, stream>>>(pos, bfrag);
    attn_kernel<<<B, 512, 0, stream>>>(q, k, v, bfrag, out);
}

// Round 11
// 108.619 us; speedup vs baseline: 1.0219x; 1.0219x over previous
//
#include <hip/hip_runtime.h>

typedef __attribute__((ext_vector_type(4))) _Float16 f16x4;
typedef __attribute__((ext_vector_type(8))) _Float16 f16x8;
typedef __attribute__((ext_vector_type(4))) float f32x4;

#define NWIN 49
#define NH 8
#define CCH 256

// cvt_pkrtz returns '__fp16 ext_vector(2)' — bit-cast through uint
__device__ __forceinline__ uint cvt2_u32(float a, float b) {
    auto t = __builtin_amdgcn_cvt_pkrtz(a, b);
    return *(uint*)&t;
}
__device__ __forceinline__ f16x4 mk4(uint a, uint b) {
    union { uint u[2]; f16x4 v; } x;
    x.u[0] = a; x.u[1] = b;
    return x.v;
}
__device__ __forceinline__ f16x8 mk8(uint a, uint b, uint c, uint d) {
    union { uint u[4]; f16x8 v; } x;
    x.u[0] = a; x.u[1] = b; x.u[2] = c; x.u[3] = d;
    return x.v;
}

// --- Kernel A: pos MLP table, (169, 8) fp32 ---
__global__ void pos_mlp_kernel(const float* __restrict__ W1, const float* __restrict__ b1,
                               const float* __restrict__ W2, const float* __restrict__ b2,
                               float* __restrict__ pos) {
    int idx = blockIdx.x * blockDim.x + threadIdx.x;
    if (idx >= 169) return;
    float bh = (float)(idx / 13) - 6.0f;
    float bw = (float)(idx % 13) - 6.0f;
    float outv[NH];
#pragma unroll
    for (int t = 0; t < NH; ++t) outv[t] = b2[t];
    for (int u = 0; u < 64; ++u) {
        float hv = fmaf(bh, W1[u], fmaf(bw, W1[64 + u], b1[u]));
        hv = fmaxf(hv, 0.0f);
#pragma unroll
        for (int t = 0; t < NH; ++t) outv[t] = fmaf(hv, W2[u * NH + t], outv[t]);
    }
#pragma unroll
    for (int t = 0; t < NH; ++t) pos[idx * NH + t] = outv[t];
}

// --- Kernel B: bias (×log2e) in S^T MFMA C/D fragment layout, -1e30 mask for j>=49 ---
__global__ void bias_frag_kernel(const float* __restrict__ pos, float* __restrict__ bfrag) {
    int blk = blockIdx.x;           // ((h*4 + jt)*4 + it), 128 blocks
    int it = blk & 3, jt = (blk >> 2) & 3, h = blk >> 4;
    int lane = threadIdx.x;
    int g = lane >> 4, l15 = lane & 15;
    int i = it * 16 + l15;
    float4 v;
    float* vp = (float*)&v;
#pragma unroll
    for (int r = 0; r < 4; ++r) {
        int j = jt * 16 + g * 4 + r;
        float val;
        if (j >= NWIN) val = -1e30f;                       // exp2 -> 0 (kills clamped K rows)
        else if (i >= NWIN) val = 0.0f;
        else {
            int rel = (i / 7 - j / 7 + 6) * 13 + (i % 7 - j % 7 + 6);
            val = pos[rel * NH + h] * 1.4426950408889634f; // fold log2e
        }
        vp[r] = val;
    }
    *(float4*)(bfrag + (size_t)blk * 256 + lane * 4) = v;
}

// --- Kernel C: 512 threads = 8 waves = 8 heads of ONE window; ZERO LDS.
//     QK^T C/D fragments feed PV directly as 16x16x16 A-operands (in-register P).
__global__ __launch_bounds__(512, 3) void attn_kernel(
    const float* __restrict__ q, const float* __restrict__ k,
    const float* __restrict__ v, const float* __restrict__ bfrag,
    float* __restrict__ out) {
    // Bijective XCD swizzle (gridDim.x = 2048, divisible by 8)
    const int nper = (int)(gridDim.x >> 3);
    const int b = ((int)blockIdx.x & 7) * nper + ((int)blockIdx.x >> 3);

    const int tid = threadIdx.x;
    const int w = tid >> 6, lane = tid & 63;   // w = head
    const int h = w;
    const int g = lane >> 4, l15 = lane & 15;  // g in [0,4)
    const size_t base = (size_t)b * (NWIN * CCH) + h * 32;

    // ======== Phase 0: issue Q/K loads + V loads (B-frag pattern for 16x16x16) ========
    float4 kraw[4][2], qraw[4][2];
#pragma unroll
    for (int t = 0; t < 4; ++t) {
        int row = t * 16 + l15;
        int rc = row < NWIN ? row : NWIN - 1;    // clamp: garbage killed downstream
        const float* kp = k + base + (size_t)rc * CCH + g * 8;
        const float* qp = q + base + (size_t)rc * CCH + g * 8;
        kraw[t][0] = *(const float4*)kp; kraw[t][1] = *(const float4*)(kp + 4);
        qraw[t][0] = *(const float4*)qp; qraw[t][1] = *(const float4*)(qp + 4);
    }
    float vv[4][2][4];   // [jt][nt][r] = V[jt*16+4g+r][nt*16+l15], clamped
#pragma unroll
    for (int jt = 0; jt < 4; ++jt)
#pragma unroll
        for (int nt = 0; nt < 2; ++nt)
#pragma unroll
            for (int r = 0; r < 4; ++r) {
                int j = jt * 16 + 4 * g + r;
                int jc = j < NWIN ? j : NWIN - 1;   // P[j>=49]=0 -> contributes 0
                vv[jt][nt][r] = v[base + (size_t)jc * CCH + nt * 16 + l15];
            }

    // ---- pin QK (drain); V stays in flight ----
#pragma unroll
    for (int t = 0; t < 4; ++t)
        asm volatile("" :: "v"(kraw[t][0].x), "v"(kraw[t][1].x),
                           "v"(qraw[t][0].x), "v"(qraw[t][1].x));

    // ======== Phase 1: convert Q/K to fp16 fragments (RTZ) ========
    f16x8 ka16[4], qb16[4];
#pragma unroll
    for (int t = 0; t < 4; ++t) {
        float4 a = kraw[t][0], c = kraw[t][1];
        ka16[t] = mk8(cvt2_u32(a.x, a.y), cvt2_u32(a.z, a.w),
                      cvt2_u32(c.x, c.y), cvt2_u32(c.z, c.w));
        float4 d = qraw[t][0], e = qraw[t][1];
        qb16[t] = mk8(cvt2_u32(d.x, d.y), cvt2_u32(d.z, d.w),
                      cvt2_u32(e.x, e.y), cvt2_u32(e.z, e.w));
    }

    // ======== Phase 2: QK^T (swapped): acc[jt][it] = S^T tile ========
    f32x4 acc[4][4];
#pragma unroll
    for (int jt = 0; jt < 4; ++jt)
#pragma unroll
        for (int it = 0; it < 4; ++it) {
            f32x4 a = {0.f, 0.f, 0.f, 0.f};
            acc[jt][it] = __builtin_amdgcn_mfma_f32_16x16x32_f16(ka16[jt], qb16[it], a, 0, 0, 0);
        }

    // ---- bias fragments now (L2-hot table; hidden under MFMA drain + softmax) ----
    f32x4 bb[4][4];
#pragma unroll
    for (int jt = 0; jt < 4; ++jt)
#pragma unroll
        for (int it = 0; it < 4; ++it)
            bb[jt][it] = *(const f32x4*)(bfrag + (size_t)((h * 4 + jt) * 4 + it) * 256 + lane * 4);

    // ======== Phase 3: softmax per column i; P stays in REGISTERS as 16x16x16 A-frags ========
    // acc[jt][it][r] = P[i=it*16+l15][j=jt*16+4g+r]  ==  A-frag(row=l15, k=4g+r) of tile (it,jt)
    const float scale2 = 0.17677669529663687f * 1.4426950408889634f;
    f16x4 pfrag[4][4];   // [jt][it]
#pragma unroll
    for (int it = 0; it < 4; ++it) {
        float p[16];
        float s = 0.0f;
#pragma unroll
        for (int jt = 0; jt < 4; ++jt)
#pragma unroll
            for (int r = 0; r < 4; ++r) {
                float e = __builtin_amdgcn_exp2f(fmaf(acc[jt][it][r], scale2, bb[jt][it][r]));
                p[jt * 4 + r] = e;
                s += e;
            }
        s += __shfl_xor(s, 16);
        s += __shfl_xor(s, 32);
        const float inv = 1.0f / s;
#pragma unroll
        for (int jt = 0; jt < 4; ++jt)
            pfrag[jt][it] = mk4(cvt2_u32(p[jt * 4 + 0] * inv, p[jt * 4 + 1] * inv),
                                cvt2_u32(p[jt * 4 + 2] * inv, p[jt * 4 + 3] * inv));
    }

    // ---- pin V + convert to fp16 B-frags ----
#pragma unroll
    for (int jt = 0; jt < 4; ++jt)
        asm volatile("" :: "v"(vv[jt][0][0]), "v"(vv[jt][0][3]),
                           "v"(vv[jt][1][0]), "v"(vv[jt][1][3]));
    f16x4 vfrag[4][2];
#pragma unroll
    for (int jt = 0; jt < 4; ++jt)
#pragma unroll
        for (int nt = 0; nt < 2; ++nt)
            vfrag[jt][nt] = mk4(cvt2_u32(vv[jt][nt][0], vv[jt][nt][1]),
                                cvt2_u32(vv[jt][nt][2], vv[jt][nt][3]));

    // ======== Phase 4: PV — 32x mfma_f32_16x16x16_f16, P never leaves registers ========
    f32x4 oacc[4][2];
#pragma unroll
    for (int mt = 0; mt < 4; ++mt)
#pragma unroll
        for (int nt = 0; nt < 2; ++nt) oacc[mt][nt] = (f32x4){0.f, 0.f, 0.f, 0.f};
#pragma unroll
    for (int jt = 0; jt < 4; ++jt)
#pragma unroll
        for (int mt = 0; mt < 4; ++mt)
#pragma unroll
            for (int nt = 0; nt < 2; ++nt)
                oacc[mt][nt] = __builtin_amdgcn_mfma_f32_16x16x16f16(pfrag[jt][mt], vfrag[jt][nt],
                                                                     oacc[mt][nt], 0, 0, 0);

    // ======== Phase 5: store (C/D: row i = mt*16+4g+r, col d = nt*16+l15) ========
#pragma unroll
    for (int mt = 0; mt < 4; ++mt)
#pragma unroll
        for (int r = 0; r < 4; ++r) {
            int i = mt * 16 + g * 4 + r;
            if (i < NWIN) {
                float* op = out + base + (size_t)i * CCH + l15;
                op[0]  = oacc[mt][0][r];
                op[16] = oacc[mt][1][r];
            }
        }
}

extern "C" void kernel_launch(void* const* d_in, const int* in_sizes, int n_in,
                              void* d_out, int out_size, void* d_ws, size_t ws_size,
                              hipStream_t stream) {
    const float* q  = (const float*)d_in[0];
    const float* k  = (const float*)d_in[1];
    const float* v  = (const float*)d_in[2];
    const float* W1 = (const float*)d_in[3];
    const float* b1 = (const float*)d_in[4];
    const float* W2 = (const float*)d_in[5];
    const float* b2 = (const float*)d_in[6];

    float* pos   = (float*)d_ws;                       // 169*8 fp32
    float* bfrag = (float*)((char*)d_ws + 8192);       // 128*256 fp32 = 131072 B
    float* out   = (float*)d_out;

    const int B = in_sizes[0] / (NWIN * CCH);          // 2048 (divisible by 8)

    pos_mlp_kernel<<<1, 192, 0, stream>>>(W1, b1, W2, b2, pos);
    bias_frag_kernel<<<128, 64, 0, stream>>>(pos, bfrag);
    attn_kernel<<<B, 512, 0, stream>>>(q, k, v, bfrag, out);
}